// Round 11
// baseline (52038.226 us; speedup 1.0000x reference)
//
#include <hip/hip_runtime.h>

// Problem constants
#define BB 2048   // batch
#define TT 128    // timesteps
#define VV 25     // input features
#define HH 512    // hidden
#define NC 100    // classes

typedef __attribute__((ext_vector_type(8))) _Float16 half8;
typedef __attribute__((ext_vector_type(4))) float f32x4;

__device__ __forceinline__ float fsigmoid(float x) { return 1.0f / (1.0f + __expf(-x)); }
__device__ __forceinline__ float ftanh(float x) {
    float e = __expf(2.0f * x);
    return 1.0f - 2.0f / (e + 1.0f);
}

// ---- XCD-L2-coherent h exchange (rounds 5-10 proven) ----
// Group blocks share one XCD (bx%8 round-robin remap); h stores plain
// (write-through L1 -> XCD L2), h loads sc0 (bypass per-CU L1). Flags sc0
// (r10 proved the sc0 fast path works: a triggered fallback would have
// cost ~43ms; observed 1.48ms). Fallback poll kept (costs one branch).
__device__ __forceinline__ half8 gload_l2(const _Float16* p) {
    half8 r;
    asm volatile("global_load_dwordx4 %0, %1, off sc0" : "=v"(r) : "v"(p) : "memory");
    return r;
}
__device__ __forceinline__ void wait_vm0() {
    asm volatile("s_waitcnt vmcnt(0)" ::: "memory");
    __builtin_amdgcn_sched_barrier(0);
}
// counted wait: ra (2 asm loads) retired; this-iteration's 8 B-weight
// loads stay in flight (the only vm ops issued after ra).
__device__ __forceinline__ void wait_vm8() {
    asm volatile("s_waitcnt vmcnt(8)" ::: "memory");
    __builtin_amdgcn_sched_barrier(0);
}
// LDS-only barrier (global prefetches stay in flight across it).
__device__ __forceinline__ void bar_lgkm() {
    asm volatile("s_waitcnt lgkmcnt(0)" ::: "memory");
    __builtin_amdgcn_sched_barrier(0);
    __builtin_amdgcn_s_barrier();
    asm volatile("" ::: "memory");
}

// ---- prep: weights -> MFMA-fragment-native fp16 layout ----
__global__ __launch_bounds__(256) void prep_whh_t(const float* __restrict__ W,
                                                  _Float16* __restrict__ WT) {
    int i = blockIdx.x * 256 + threadIdx.x;   // 2048 n x 64 kq, grid 512
    int n = i & 2047, kq = i >> 11;
    half8 h8;
    #pragma unroll
    for (int j = 0; j < 8; ++j) h8[j] = (_Float16)W[(size_t)n * HH + kq * 8 + j];  // RNE cvt
    ((half8*)WT)[(size_t)kq * 2048 + n] = h8;
}

__global__ __launch_bounds__(256) void prep_wih_t(const float* __restrict__ W,
                                                  _Float16* __restrict__ WT) {
    int i = blockIdx.x * 256 + threadIdx.x;   // 2048 n x 4 kq, grid 32
    int n = i & 2047, kq4 = i >> 11;
    half8 h8;
    #pragma unroll
    for (int j = 0; j < 8; ++j) {
        int k = kq4 * 8 + j;
        h8[j] = (k < VV) ? (_Float16)W[(size_t)n * VV + k] : (_Float16)0.0f;
    }
    ((half8*)WT)[(size_t)(64 + kq4) * 2048 + n] = h8;
}

// Persistent LSTM, round 11: round 10's RUN-PROVEN structure; ONE
// mechanism changed — W_hh B-fragments for K32 chunks 0..5 are REGISTER-
// RESIDENT across all 128 steps (96 VGPR, loaded once), chunks 6,7 are
// preloaded in the barrier window, only chunks 8..15 stream in-loop.
//
// Rationale (r6 vs r10 data): barrier-transport changes are exhausted
// (flag scope = neutral); the persistent step (11.6us) ~= the old
// launch-per-step (12.2us) -> the INNER LOOP dominates. B streaming was
// 68KB issued/wave/step from L2 with a marginal distance-2 prefetch;
// residency removes 6/16 of the stream and all its latency exposure,
// and the remaining stream keeps exact counted waits:
//   iters 0-2: only ra in flight -> vmcnt(0)
//   iters 3-6: ra + 8 B loads (pf 8..15) -> vmcnt(8)
// VGPR 128 -> ~230, still 2 waves/SIMD (cliff at 256; launch_bounds caps).
__global__ __launch_bounds__(256, 2) void lstm_persist(
    const float* __restrict__ msg,
    const _Float16* __restrict__ WT,
    const float* __restrict__ b_ih, const float* __restrict__ b_hh,
    _Float16* __restrict__ h0g, _Float16* __restrict__ h1g,
    unsigned* __restrict__ ctr)
{
    const int bx = blockIdx.x;
    const int grp = (bx & 7) | ((bx >> 7) << 3);   // batch group: 64 rows
    const int member = (bx >> 3) & 15;             // j-block within group
    const int b0 = grp * 64;
    const int j0 = member * 32;
    const int tid = threadIdx.x;
    const int lane = tid & 63;
    const int w = tid >> 6;
    const int wm = w & 1, wn = w >> 1;
    const int col = lane & 15, quad = lane >> 4;
    const int jj = j0 + wn * 16 + col;

    // [buf][row][k]; row stride 72 halves: frag b128 reads conflict-free.
    __shared__ _Float16 Abuf[2][64][72];

    // ---- loop-invariant state ----
    float bias[4];
    #pragma unroll
    for (int g = 0; g < 4; ++g) bias[g] = b_ih[g * HH + jj] + b_hh[g * HH + jj];

    const int arow = tid >> 2, aseg = (tid & 3) << 4;
    const size_t aoff = (size_t)(b0 + arow) * HH + aseg;
    const _Float16* a0 = h0g + aoff;    // A staging base per h-plane
    const _Float16* a1 = h1g + aoff;

    const half8* WT8 = (const half8*)WT;
    int bidx[4];
    #pragma unroll
    for (int g = 0; g < 4; ++g) bidx[g] = quad * 2048 + g * HH + jj;

    // h store base: rows b0+wm*32+quad*4 (+ tm*16 + reg)
    const size_t soff = (size_t)(b0 + wm * 32 + quad * 4) * HH + jj;
    _Float16* s0 = h0g + soff;
    _Float16* s1 = h1g + soff;

    // per-member flag words, 64B apart
    unsigned* myflag = ctr + (grp * 16 + member) * 16;
    unsigned* pollflag = ctr + (grp * 16 + (lane & 15)) * 16;

    float cv[2][4] = {{0.f,0.f,0.f,0.f},{0.f,0.f,0.f,0.f}};  // c in registers

    const float* mp[2];
    #pragma unroll
    for (int tm = 0; tm < 2; ++tm)
        mp[tm] = msg + (size_t)(b0 + wm * 32 + tm * 16 + col) * TT * VV;

    // chunk-16 (x-projection) B frags: constant, register-resident
    half8 Bx[4];
    #pragma unroll
    for (int g = 0; g < 4; ++g) Bx[g] = WT8[16 * 8192 + bidx[g]];

    // chunks 0..5 B frags: register-resident for all 128 steps (96 VGPR)
    half8 Bres[6][4];
    #pragma unroll
    for (int cc = 0; cc < 6; ++cc)
        #pragma unroll
        for (int g = 0; g < 4; ++g) Bres[cc][g] = WT8[cc * 8192 + bidx[g]];

    half8 Bs[2][4];    // stream slots for chunks 6..15 (slot = chunk&1)
    f32x4 acc[2][4];   // [tm][gate]; at loop entry for step t: bias + x_t@Wih

    // ---- pre-loop: acc for t=0 ----
    {
        float xv[2][8];
        #pragma unroll
        for (int tm = 0; tm < 2; ++tm)
            #pragma unroll
            for (int j = 0; j < 8; ++j) {
                int k = quad * 8 + j;
                xv[tm][j] = (k < VV) ? mp[tm][k] : 0.0f;
            }
        #pragma unroll
        for (int g = 0; g < 4; ++g) {
            f32x4 bv = {bias[g], bias[g], bias[g], bias[g]};
            acc[0][g] = bv;
            acc[1][g] = bv;
        }
        #pragma unroll
        for (int tm = 0; tm < 2; ++tm) {
            half8 xh;
            #pragma unroll
            for (int j = 0; j < 8; ++j) xh[j] = (_Float16)xv[tm][j];
            #pragma unroll
            for (int g = 0; g < 4; ++g)
                acc[tm][g] = __builtin_amdgcn_mfma_f32_16x16x32_f16(xh, Bx[g], acc[tm][g], 0, 0, 0);
        }
    }

    for (int t = 0; t < TT; ++t) {
        if (t > 0) {   // h-projection: 16 K32 chunks over h_{t-1}
            const _Float16* aph = (t & 1) ? a1 : a0;   // hin plane

            // prologue: A chunk0 -> LDS buf0; chunk1 -> ra. (Bs[0]=c6,
            // Bs[1]=c7 were prefetched in the previous barrier window.)
            half8 ra0 = gload_l2(aph);
            half8 ra1 = gload_l2(aph + 8);
            wait_vm0();
            *(half8*)&Abuf[0][arow][aseg]     = ra0;
            *(half8*)&Abuf[0][arow][aseg + 8] = ra1;
            ra0 = gload_l2(aph + 64);
            ra1 = gload_l2(aph + 72);
            bar_lgkm();

            #pragma unroll
            for (int it = 0; it < 8; ++it) {
                const int buf = it & 1;
                #pragma unroll
                for (int kk = 0; kk < 2; ++kk) {
                    const int cc = it * 2 + kk;   // K32 chunk 0..15
                    half8 ahf[2];
                    #pragma unroll
                    for (int tm = 0; tm < 2; ++tm)
                        ahf[tm] = *(const half8*)&Abuf[buf][wm * 32 + tm * 16 + col][kk * 32 + quad * 8];
                    #pragma unroll
                    for (int tm = 0; tm < 2; ++tm)
                        #pragma unroll
                        for (int g = 0; g < 4; ++g) {
                            // B operand: resident (0..5) / stream (6..15);
                            // cc is compile-time constant after unroll.
                            const half8 bf = (cc < 6) ? Bres[cc][g] : Bs[cc & 1][g];
                            acc[tm][g] = __builtin_amdgcn_mfma_f32_16x16x32_f16(ahf[tm], bf, acc[tm][g], 0, 0, 0);
                        }
                    const int pf = cc + 2;        // stream prefetch 8..15
                    if (pf >= 8 && pf <= 15) {
                        #pragma unroll
                        for (int g = 0; g < 4; ++g) Bs[pf & 1][g] = WT8[pf * 8192 + bidx[g]];
                    }
                }
                if (it < 7) {
                    // exact counted wait: ra retired; this iteration's B
                    // prefetches (0 for it<3, 8 for it>=3) stay in flight.
                    if (it < 3) wait_vm0(); else wait_vm8();
                    *(half8*)&Abuf[buf ^ 1][arow][aseg]     = ra0;
                    *(half8*)&Abuf[buf ^ 1][arow][aseg + 8] = ra1;
                    if (it < 6) {
                        ra0 = gload_l2(aph + (it + 2) * 64);
                        ra1 = gload_l2(aph + (it + 2) * 64 + 8);
                    }
                    bar_lgkm();
                }
            }
        }

        // ---- cell update: c in registers; plain h stores -> XCD L2 ----
        // C/D layout: col=lane&15 (=n), row=quad*4+reg  [m89]
        _Float16* hop = (t & 1) ? s0 : s1;      // h_t plane
        #pragma unroll
        for (int tm = 0; tm < 2; ++tm)
            #pragma unroll
            for (int reg = 0; reg < 4; ++reg) {
                float i_ = fsigmoid(acc[tm][0][reg]);
                float f_ = fsigmoid(acc[tm][1][reg]);
                float g_ = ftanh(acc[tm][2][reg]);
                float o_ = fsigmoid(acc[tm][3][reg]);
                float cn = __builtin_fmaf(f_, cv[tm][reg], i_ * g_);
                cv[tm][reg] = cn;
                hop[(size_t)(tm * 16 + reg) * HH] = (_Float16)(o_ * ftanh(cn));
            }

        if (t + 1 < TT) {
            // ---- arrival: drain h stores, then one sc0 flag store ----
            __syncthreads();   // vmcnt(0): h_t retired into XCD L2
            if (tid == 0) {
                unsigned v = (unsigned)(t + 1);
                asm volatile("global_store_dword %0, %1, off sc0"
                             :: "v"(myflag), "v"(v) : "memory");
            }

            // ---- overlap window: all h-independent t+1 work ----
            #pragma unroll
            for (int tm = 0; tm < 2; ++tm) mp[tm] += VV;
            float xv[2][8];
            #pragma unroll
            for (int tm = 0; tm < 2; ++tm)
                #pragma unroll
                for (int j = 0; j < 8; ++j) {
                    int k = quad * 8 + j;
                    xv[tm][j] = (k < VV) ? mp[tm][k] : 0.0f;
                }
            #pragma unroll
            for (int g = 0; g < 4; ++g) {
                f32x4 bv = {bias[g], bias[g], bias[g], bias[g]};
                acc[0][g] = bv;
                acc[1][g] = bv;
            }
            #pragma unroll
            for (int tm = 0; tm < 2; ++tm) {
                half8 xh;
                #pragma unroll
                for (int j = 0; j < 8; ++j) xh[j] = (_Float16)xv[tm][j];
                #pragma unroll
                for (int g = 0; g < 4; ++g)
                    acc[tm][g] = __builtin_amdgcn_mfma_f32_16x16x32_f16(xh, Bx[g], acc[tm][g], 0, 0, 0);
            }
            // stream-slot preload for next step: chunks 6 and 7
            #pragma unroll
            for (int g = 0; g < 4; ++g) {
                Bs[0][g] = WT8[6 * 8192 + bidx[g]];
                Bs[1][g] = WT8[7 * 8192 + bidx[g]];
            }

            // ---- departure: wave0 polls all 16 flags, one load/iter.
            //      sc0 fast path; sc0sc1 fallback after 4096 spins ----
            if (w == 0) {
                const unsigned tgt = (unsigned)(t + 1);
                int spins = 0;
                for (;;) {
                    unsigned f;
                    if (spins < 4096) {
                        asm volatile("global_load_dword %0, %1, off sc0\n\t"
                                     "s_waitcnt vmcnt(0)"
                                     : "=v"(f) : "v"(pollflag) : "memory");
                    } else {
                        asm volatile("global_load_dword %0, %1, off sc0 sc1\n\t"
                                     "s_waitcnt vmcnt(0)"
                                     : "=v"(f) : "v"(pollflag) : "memory");
                    }
                    if (__all((int)(f >= tgt))) break;
                    ++spins;
                    __builtin_amdgcn_s_sleep(1);
                }
                __builtin_amdgcn_sched_barrier(0);
            }
            __syncthreads();
        }
    }
}

// out[b, cls] = dot(h, W_fc[cls]) + b_fc[cls]. 4 rows/block.
__global__ __launch_bounds__(256) void fc_kernel(
    const _Float16* __restrict__ h, const float* __restrict__ W_fc,
    const float* __restrict__ b_fc, float* __restrict__ out)
{
    __shared__ float hs[4][HH];
    const int b0 = blockIdx.x * 4;
    for (int i = threadIdx.x; i < 4 * HH; i += 256) {
        int r = i >> 9, k = i & 511;
        hs[r][k] = (float)h[(size_t)(b0 + r) * HH + k];
    }
    __syncthreads();
    const int tid = threadIdx.x;
    if (tid < 2 * NC) {
        int r = tid / NC, cls = tid % NC;
        const float4* wv = (const float4*)(W_fc + (size_t)cls * HH);
        const float4* h0 = (const float4*)hs[r];
        const float4* h1 = (const float4*)hs[r + 2];
        float s0 = 0.0f, s1 = 0.0f;
        #pragma unroll 4
        for (int k = 0; k < HH / 4; ++k) {
            float4 ww = wv[k];
            float4 a0 = h0[k], a1 = h1[k];
            s0 += a0.x * ww.x + a0.y * ww.y + a0.z * ww.z + a0.w * ww.w;
            s1 += a1.x * ww.x + a1.y * ww.y + a1.z * ww.z + a1.w * ww.w;
        }
        out[(size_t)(b0 + r) * NC + cls] = s0 + b_fc[cls];
        out[(size_t)(b0 + r + 2) * NC + cls] = s1 + b_fc[cls];
    }
}

extern "C" void kernel_launch(void* const* d_in, const int* in_sizes, int n_in,
                              void* d_out, int out_size, void* d_ws, size_t ws_size,
                              hipStream_t stream) {
    const float* msg  = (const float*)d_in[0];
    const float* W_ih = (const float*)d_in[1];
    const float* W_hh = (const float*)d_in[2];
    const float* b_ih = (const float*)d_in[3];
    const float* b_hh = (const float*)d_in[4];
    const float* W_fc = (const float*)d_in[5];
    const float* b_fc = (const float*)d_in[6];
    float* out = (float*)d_out;

    // ws: h0 h1 (fp16, 2MB ea) | WT (fp16, 2.23MB) | flags (32KB)
    _Float16* h0 = (_Float16*)d_ws;
    _Float16* h1 = h0 + (size_t)BB * HH;
    _Float16* WT = h1 + (size_t)BB * HH;
    unsigned* ctr = (unsigned*)(WT + (size_t)68 * 2048 * 8);

    hipMemsetAsync(ctr, 0, 32 * 16 * 16 * sizeof(unsigned), stream);

    prep_whh_t<<<512, 256, 0, stream>>>(W_hh, WT);
    prep_wih_t<<<32, 256, 0, stream>>>(W_ih, WT);

    lstm_persist<<<512, 256, 0, stream>>>(msg, WT, b_ih, b_hh, h0, h1, ctr);

    // t=127 (odd) writes h0
    fc_kernel<<<BB / 4, 256, 0, stream>>>(h0, W_fc, b_fc, out);
}

// Round 12
// 31626.956 us; speedup vs baseline: 1.6454x; 1.6454x over previous
//
#include <hip/hip_runtime.h>

// Problem constants
#define BB 2048   // batch
#define TT 128    // timesteps
#define VV 25     // input features
#define HH 512    // hidden
#define NC 100    // classes

typedef __attribute__((ext_vector_type(8))) _Float16 half8;
typedef __attribute__((ext_vector_type(4))) float f32x4;

__device__ __forceinline__ float fsigmoid(float x) { return 1.0f / (1.0f + __expf(-x)); }
__device__ __forceinline__ float ftanh(float x) {
    float e = __expf(2.0f * x);
    return 1.0f - 2.0f / (e + 1.0f);
}

// ---- XCD-L2-coherent h exchange (rounds 5-10 proven) ----
// Group blocks share one XCD (bx%8 round-robin remap); h stores plain
// (write-through L1 -> XCD L2), h loads sc0 (bypass per-CU L1). Flags sc0
// with sc0sc1 fallback poll (r10-proven).
__device__ __forceinline__ half8 gload_l2(const _Float16* p) {
    half8 r;
    asm volatile("global_load_dwordx4 %0, %1, off sc0" : "=v"(r) : "v"(p) : "memory");
    return r;
}
// LDS-only barrier (global prefetches stay in flight across it).
__device__ __forceinline__ void bar_lgkm() {
    asm volatile("s_waitcnt lgkmcnt(0)" ::: "memory");
    __builtin_amdgcn_sched_barrier(0);
    __builtin_amdgcn_s_barrier();
    asm volatile("" ::: "memory");
}

// ---- prep: weights -> MFMA-fragment-native fp16 layout ----
__global__ __launch_bounds__(256) void prep_whh_t(const float* __restrict__ W,
                                                  _Float16* __restrict__ WT) {
    int i = blockIdx.x * 256 + threadIdx.x;   // 2048 n x 64 kq, grid 512
    int n = i & 2047, kq = i >> 11;
    half8 h8;
    #pragma unroll
    for (int j = 0; j < 8; ++j) h8[j] = (_Float16)W[(size_t)n * HH + kq * 8 + j];  // RNE cvt
    ((half8*)WT)[(size_t)kq * 2048 + n] = h8;
}

__global__ __launch_bounds__(256) void prep_wih_t(const float* __restrict__ W,
                                                  _Float16* __restrict__ WT) {
    int i = blockIdx.x * 256 + threadIdx.x;   // 2048 n x 4 kq, grid 32
    int n = i & 2047, kq4 = i >> 11;
    half8 h8;
    #pragma unroll
    for (int j = 0; j < 8; ++j) {
        int k = kq4 * 8 + j;
        h8[j] = (k < VV) ? (_Float16)W[(size_t)n * VV + k] : (_Float16)0.0f;
    }
    ((half8*)WT)[(size_t)(64 + kq4) * 2048 + n] = h8;
}

// Persistent LSTM, round 12: r10's RUN-PROVEN protocol with the step body
// restructured as STAGE-THEN-COMPUTE (one mechanism):
//   phase 1: the whole 64x512 h tile -> LDS (chunk-major [16][64][32],
//            exactly 64KB) via a 3-batch register ring of sc0 loads with
//            exact counted vmcnt(4/2/0) waits (pipeline depth 6 loads).
//   ONE bar_lgkm.
//   phase 2: straight-line 16 chunks x 8 MFMA, zero barriers/waits — only
//            the Bs[2] register-ring B prefetch (plain loads; compiler
//            inserts counted waits) at distance 2.
// vs r10: 8 bar_lgkm/step -> 1, all wait_vm8 gone, staging 2-deep -> 6-deep.
// Rationale: sync-transport ladder exhausted (r6->r10 flag scope neutral);
// persistent step ~= launch step -> the in-loop barrier/wait structure IS
// the remaining cost. r11 lesson: VGPR demand kept at r10's level (~128) —
// the allocator spills rather than grow past it (52ms scratch disaster).
// Arithmetic order identical to r10 -> bit-identical output.
__global__ __launch_bounds__(256, 2) void lstm_persist(
    const float* __restrict__ msg,
    const _Float16* __restrict__ WT,
    const float* __restrict__ b_ih, const float* __restrict__ b_hh,
    _Float16* __restrict__ h0g, _Float16* __restrict__ h1g,
    unsigned* __restrict__ ctr)
{
    const int bx = blockIdx.x;
    const int grp = (bx & 7) | ((bx >> 7) << 3);   // batch group: 64 rows
    const int member = (bx >> 3) & 15;             // j-block within group
    const int b0 = grp * 64;
    const int j0 = member * 32;
    const int tid = threadIdx.x;
    const int lane = tid & 63;
    const int w = tid >> 6;
    const int wm = w & 1, wn = w >> 1;
    const int col = lane & 15, quad = lane >> 4;
    const int jj = j0 + wn * 16 + col;

    // chunk-major A tile: [K32 chunk][row][32 halves] = 65536 B exactly.
    // Frag read (phase 2): lanes (col=row, quad) -> dword bank
    // (row*16 + quad*4)%32: 8 uniform starts x 8 lanes = conflict-free
    // minimum for b128. Same class as the proven 72-half stride.
    __shared__ _Float16 Abuf[16][64][32];

    // ---- loop-invariant state ----
    float bias[4];
    #pragma unroll
    for (int g = 0; g < 4; ++g) bias[g] = b_ih[g * HH + jj] + b_hh[g * HH + jj];

    // staging: thread (row = tid>>2, q = tid&3) covers halves q*8 within
    // each 32-half chunk of its row: 16 x 16B loads per step.
    const int arow = tid >> 2, aq = tid & 3;
    const size_t aoff = (size_t)(b0 + arow) * HH + aq * 8;
    const _Float16* a0 = h0g + aoff;
    const _Float16* a1 = h1g + aoff;

    const half8* WT8 = (const half8*)WT;
    int bidx[4];
    #pragma unroll
    for (int g = 0; g < 4; ++g) bidx[g] = quad * 2048 + g * HH + jj;

    // h store base: rows b0+wm*32+quad*4 (+ tm*16 + reg)
    const size_t soff = (size_t)(b0 + wm * 32 + quad * 4) * HH + jj;
    _Float16* s0 = h0g + soff;
    _Float16* s1 = h1g + soff;

    // per-member flag words, 64B apart
    unsigned* myflag = ctr + (grp * 16 + member) * 16;
    unsigned* pollflag = ctr + (grp * 16 + (lane & 15)) * 16;

    float cv[2][4] = {{0.f,0.f,0.f,0.f},{0.f,0.f,0.f,0.f}};  // c in registers

    const float* mp[2];
    #pragma unroll
    for (int tm = 0; tm < 2; ++tm)
        mp[tm] = msg + (size_t)(b0 + wm * 32 + tm * 16 + col) * TT * VV;

    // chunk-16 (x-projection) B frags: constant, register-resident
    half8 Bx[4];
    #pragma unroll
    for (int g = 0; g < 4; ++g) Bx[g] = WT8[16 * 8192 + bidx[g]];

    half8 Bs[2][4];    // B stream ring (slot = chunk & 1)
    f32x4 acc[2][4];   // [tm][gate]; at loop entry for step t: bias + x_t@Wih

    // ---- pre-loop: acc for t=0 ----
    {
        float xv[2][8];
        #pragma unroll
        for (int tm = 0; tm < 2; ++tm)
            #pragma unroll
            for (int j = 0; j < 8; ++j) {
                int k = quad * 8 + j;
                xv[tm][j] = (k < VV) ? mp[tm][k] : 0.0f;
            }
        #pragma unroll
        for (int g = 0; g < 4; ++g) {
            f32x4 bv = {bias[g], bias[g], bias[g], bias[g]};
            acc[0][g] = bv;
            acc[1][g] = bv;
        }
        #pragma unroll
        for (int tm = 0; tm < 2; ++tm) {
            half8 xh;
            #pragma unroll
            for (int j = 0; j < 8; ++j) xh[j] = (_Float16)xv[tm][j];
            #pragma unroll
            for (int g = 0; g < 4; ++g)
                acc[tm][g] = __builtin_amdgcn_mfma_f32_16x16x32_f16(xh, Bx[g], acc[tm][g], 0, 0, 0);
        }
    }

    for (int t = 0; t < TT; ++t) {
        if (t > 0) {   // h-projection over h_{t-1}
            const _Float16* aph = (t & 1) ? a1 : a0;   // hin plane

            // ---- phase 1: stage all 16 chunks (3-batch ring, 2 loads/batch)
            half8 sb[3][2];
            #pragma unroll
            for (int bt = 0; bt < 3; ++bt) {
                sb[bt][0] = gload_l2(aph + (2 * bt) * 32);
                sb[bt][1] = gload_l2(aph + (2 * bt + 1) * 32);
            }
            #pragma unroll
            for (int bt = 0; bt < 8; ++bt) {
                // exact counted wait for batch bt (older window loads are
                // forced retired too — correct, mildly conservative)
                if (bt < 6)      asm volatile("s_waitcnt vmcnt(4)" ::: "memory");
                else if (bt == 6) asm volatile("s_waitcnt vmcnt(2)" ::: "memory");
                else              asm volatile("s_waitcnt vmcnt(0)" ::: "memory");
                __builtin_amdgcn_sched_barrier(0);
                const int sl = bt % 3;
                *(half8*)&Abuf[2 * bt][arow][aq * 8]     = sb[sl][0];
                *(half8*)&Abuf[2 * bt + 1][arow][aq * 8] = sb[sl][1];
                if (bt + 3 < 8) {
                    sb[sl][0] = gload_l2(aph + (2 * (bt + 3)) * 32);
                    sb[sl][1] = gload_l2(aph + (2 * (bt + 3) + 1) * 32);
                }
            }
            bar_lgkm();   // the ONLY barrier in the step body

            // ---- phase 2: straight-line 16 chunks, compiler-scheduled ----
            #pragma unroll
            for (int cc = 0; cc < 16; ++cc) {
                half8 ahf[2];
                #pragma unroll
                for (int tm = 0; tm < 2; ++tm)
                    ahf[tm] = *(const half8*)&Abuf[cc][wm * 32 + tm * 16 + col][quad * 8];
                #pragma unroll
                for (int tm = 0; tm < 2; ++tm)
                    #pragma unroll
                    for (int g = 0; g < 4; ++g)
                        acc[tm][g] = __builtin_amdgcn_mfma_f32_16x16x32_f16(ahf[tm], Bs[cc & 1][g], acc[tm][g], 0, 0, 0);
                const int pf = cc + 2;    // distance-2 B prefetch, plain loads
                if (pf <= 15) {
                    #pragma unroll
                    for (int g = 0; g < 4; ++g) Bs[pf & 1][g] = WT8[pf * 8192 + bidx[g]];
                }
            }
        }

        // ---- cell update: c in registers; plain h stores -> XCD L2 ----
        // C/D layout: col=lane&15 (=n), row=quad*4+reg  [m89]
        _Float16* hop = (t & 1) ? s0 : s1;      // h_t plane
        #pragma unroll
        for (int tm = 0; tm < 2; ++tm)
            #pragma unroll
            for (int reg = 0; reg < 4; ++reg) {
                float i_ = fsigmoid(acc[tm][0][reg]);
                float f_ = fsigmoid(acc[tm][1][reg]);
                float g_ = ftanh(acc[tm][2][reg]);
                float o_ = fsigmoid(acc[tm][3][reg]);
                float cn = __builtin_fmaf(f_, cv[tm][reg], i_ * g_);
                cv[tm][reg] = cn;
                hop[(size_t)(tm * 16 + reg) * HH] = (_Float16)(o_ * ftanh(cn));
            }

        if (t + 1 < TT) {
            // ---- arrival: drain h stores, then one sc0 flag store ----
            __syncthreads();   // vmcnt(0): h_t retired into XCD L2
            if (tid == 0) {
                unsigned v = (unsigned)(t + 1);
                asm volatile("global_store_dword %0, %1, off sc0"
                             :: "v"(myflag), "v"(v) : "memory");
            }

            // ---- overlap window: all h-independent t+1 work ----
            #pragma unroll
            for (int tm = 0; tm < 2; ++tm) mp[tm] += VV;
            float xv[2][8];
            #pragma unroll
            for (int tm = 0; tm < 2; ++tm)
                #pragma unroll
                for (int j = 0; j < 8; ++j) {
                    int k = quad * 8 + j;
                    xv[tm][j] = (k < VV) ? mp[tm][k] : 0.0f;
                }
            #pragma unroll
            for (int g = 0; g < 4; ++g) {
                f32x4 bv = {bias[g], bias[g], bias[g], bias[g]};
                acc[0][g] = bv;
                acc[1][g] = bv;
            }
            #pragma unroll
            for (int tm = 0; tm < 2; ++tm) {
                half8 xh;
                #pragma unroll
                for (int j = 0; j < 8; ++j) xh[j] = (_Float16)xv[tm][j];
                #pragma unroll
                for (int g = 0; g < 4; ++g)
                    acc[tm][g] = __builtin_amdgcn_mfma_f32_16x16x32_f16(xh, Bx[g], acc[tm][g], 0, 0, 0);
            }
            // B-ring preload for next step: chunks 0 and 1
            #pragma unroll
            for (int g = 0; g < 4; ++g) {
                Bs[0][g] = WT8[bidx[g]];
                Bs[1][g] = WT8[8192 + bidx[g]];
            }

            // ---- departure: wave0 polls all 16 flags, one load/iter.
            //      sc0 fast path; sc0sc1 fallback after 4096 spins ----
            if (w == 0) {
                const unsigned tgt = (unsigned)(t + 1);
                int spins = 0;
                for (;;) {
                    unsigned f;
                    if (spins < 4096) {
                        asm volatile("global_load_dword %0, %1, off sc0\n\t"
                                     "s_waitcnt vmcnt(0)"
                                     : "=v"(f) : "v"(pollflag) : "memory");
                    } else {
                        asm volatile("global_load_dword %0, %1, off sc0 sc1\n\t"
                                     "s_waitcnt vmcnt(0)"
                                     : "=v"(f) : "v"(pollflag) : "memory");
                    }
                    if (__all((int)(f >= tgt))) break;
                    ++spins;
                    __builtin_amdgcn_s_sleep(1);
                }
                __builtin_amdgcn_sched_barrier(0);
            }
            __syncthreads();
        }
    }
}

// out[b, cls] = dot(h, W_fc[cls]) + b_fc[cls]. 4 rows/block.
__global__ __launch_bounds__(256) void fc_kernel(
    const _Float16* __restrict__ h, const float* __restrict__ W_fc,
    const float* __restrict__ b_fc, float* __restrict__ out)
{
    __shared__ float hs[4][HH];
    const int b0 = blockIdx.x * 4;
    for (int i = threadIdx.x; i < 4 * HH; i += 256) {
        int r = i >> 9, k = i & 511;
        hs[r][k] = (float)h[(size_t)(b0 + r) * HH + k];
    }
    __syncthreads();
    const int tid = threadIdx.x;
    if (tid < 2 * NC) {
        int r = tid / NC, cls = tid % NC;
        const float4* wv = (const float4*)(W_fc + (size_t)cls * HH);
        const float4* h0 = (const float4*)hs[r];
        const float4* h1 = (const float4*)hs[r + 2];
        float s0 = 0.0f, s1 = 0.0f;
        #pragma unroll 4
        for (int k = 0; k < HH / 4; ++k) {
            float4 ww = wv[k];
            float4 a0 = h0[k], a1 = h1[k];
            s0 += a0.x * ww.x + a0.y * ww.y + a0.z * ww.z + a0.w * ww.w;
            s1 += a1.x * ww.x + a1.y * ww.y + a1.z * ww.z + a1.w * ww.w;
        }
        out[(size_t)(b0 + r) * NC + cls] = s0 + b_fc[cls];
        out[(size_t)(b0 + r + 2) * NC + cls] = s1 + b_fc[cls];
    }
}

extern "C" void kernel_launch(void* const* d_in, const int* in_sizes, int n_in,
                              void* d_out, int out_size, void* d_ws, size_t ws_size,
                              hipStream_t stream) {
    const float* msg  = (const float*)d_in[0];
    const float* W_ih = (const float*)d_in[1];
    const float* W_hh = (const float*)d_in[2];
    const float* b_ih = (const float*)d_in[3];
    const float* b_hh = (const float*)d_in[4];
    const float* W_fc = (const float*)d_in[5];
    const float* b_fc = (const float*)d_in[6];
    float* out = (float*)d_out;

    // ws: h0 h1 (fp16, 2MB ea) | WT (fp16, 2.23MB) | flags (32KB)
    _Float16* h0 = (_Float16*)d_ws;
    _Float16* h1 = h0 + (size_t)BB * HH;
    _Float16* WT = h1 + (size_t)BB * HH;
    unsigned* ctr = (unsigned*)(WT + (size_t)68 * 2048 * 8);

    hipMemsetAsync(ctr, 0, 32 * 16 * 16 * sizeof(unsigned), stream);

    prep_whh_t<<<512, 256, 0, stream>>>(W_hh, WT);
    prep_wih_t<<<32, 256, 0, stream>>>(W_ih, WT);

    lstm_persist<<<512, 256, 0, stream>>>(msg, WT, b_ih, b_hh, h0, h1, ctr);

    // t=127 (odd) writes h0
    fc_kernel<<<BB / 4, 256, 0, stream>>>(h0, W_fc, b_fc, out);
}

// Round 13
// 1389.671 us; speedup vs baseline: 37.4464x; 22.7586x over previous
//
#include <hip/hip_runtime.h>

// Problem constants
#define BB 2048   // batch
#define TT 128    // timesteps
#define VV 25     // input features
#define HH 512    // hidden
#define NC 100    // classes

typedef __attribute__((ext_vector_type(8))) _Float16 half8;
typedef __attribute__((ext_vector_type(4))) float f32x4;

__device__ __forceinline__ float fsigmoid(float x) { return 1.0f / (1.0f + __expf(-x)); }
__device__ __forceinline__ float ftanh(float x) {
    float e = __expf(2.0f * x);
    return 1.0f - 2.0f / (e + 1.0f);
}

// ---- XCD-L2-coherent h exchange (round-5/6-proven) ----
// Group blocks share one XCD (bx%8 round-robin remap); h stores are plain
// (write-through L1 -> XCD L2), h loads sc0 (bypass stale per-CU L1, hit
// XCD L2). This is the EXACT round-6 kernel (best verified: 1382us) —
// re-anchored after rounds 7-12: sync-transport ladder exhausted (flag
// scope = neutral, r10); inner-loop restructurings all regressed (r11:
// allocator spill at +96 VGPR, 52ms; r12: stage-then-compute hit an
// unmodeled ~20x serialization with all pipes idle, 31ms). The r6 inner
// loop is a narrow codegen local optimum; this consolidates it.
__device__ __forceinline__ half8 gload_l2(const _Float16* p) {
    half8 r;
    asm volatile("global_load_dwordx4 %0, %1, off sc0" : "=v"(r) : "v"(p) : "memory");
    return r;
}
__device__ __forceinline__ void wait_vm0() {
    asm volatile("s_waitcnt vmcnt(0)" ::: "memory");
    __builtin_amdgcn_sched_barrier(0);
}
// counted wait: ra (2 asm loads) retired; this-iteration's 8 B-weight loads
// stay in flight (the only vm ops issued after ra).
__device__ __forceinline__ void wait_vm8() {
    asm volatile("s_waitcnt vmcnt(8)" ::: "memory");
    __builtin_amdgcn_sched_barrier(0);
}
// LDS-only barrier (global prefetches stay in flight across it).
__device__ __forceinline__ void bar_lgkm() {
    asm volatile("s_waitcnt lgkmcnt(0)" ::: "memory");
    __builtin_amdgcn_sched_barrier(0);
    __builtin_amdgcn_s_barrier();
    asm volatile("" ::: "memory");
}

// ---- prep: weights -> MFMA-fragment-native fp16 layout ----
__global__ __launch_bounds__(256) void prep_whh_t(const float* __restrict__ W,
                                                  _Float16* __restrict__ WT) {
    int i = blockIdx.x * 256 + threadIdx.x;   // 2048 n x 64 kq, grid 512
    int n = i & 2047, kq = i >> 11;
    half8 h8;
    #pragma unroll
    for (int j = 0; j < 8; ++j) h8[j] = (_Float16)W[(size_t)n * HH + kq * 8 + j];  // RNE cvt
    ((half8*)WT)[(size_t)kq * 2048 + n] = h8;
}

__global__ __launch_bounds__(256) void prep_wih_t(const float* __restrict__ W,
                                                  _Float16* __restrict__ WT) {
    int i = blockIdx.x * 256 + threadIdx.x;   // 2048 n x 4 kq, grid 32
    int n = i & 2047, kq4 = i >> 11;
    half8 h8;
    #pragma unroll
    for (int j = 0; j < 8; ++j) {
        int k = kq4 * 8 + j;
        h8[j] = (k < VV) ? (_Float16)W[(size_t)n * VV + k] : (_Float16)0.0f;
    }
    ((half8*)WT)[(size_t)(64 + kq4) * 2048 + n] = h8;
}

// Persistent LSTM (round-6 structure, verified 1382us):
//
// Barrier (per group of 16 blocks, per step):
//   arrival:  __syncthreads() [drains vmcnt -> h stores in L2], then
//             tid0 stores flag[grp][member] = t+1 (plain store, sc0sc1;
//             16 independent lines, no RMW, no serialization).
//   overlap:  x-values(t+1) load, acc = bias + x@Wih MFMA (chunk-16 B
//             frags permanent in Bx regs), B chunk-0/1 prefetch — all
//             h-independent, hides flag propagation.
//   depart:   wave0 lanes0-15 poll all 16 flags with ONE vector
//             global_load_dword per iteration + __all ballot; then
//             __syncthreads().
// Safety: skew within a group is provably <= 1 step (flag t+2 requires all
// members through step t+1), so the 2-plane h double-buffer suffices.
__global__ __launch_bounds__(256, 2) void lstm_persist(
    const float* __restrict__ msg,
    const _Float16* __restrict__ WT,
    const float* __restrict__ b_ih, const float* __restrict__ b_hh,
    _Float16* __restrict__ h0g, _Float16* __restrict__ h1g,
    unsigned* __restrict__ ctr)
{
    const int bx = blockIdx.x;
    const int grp = (bx & 7) | ((bx >> 7) << 3);   // batch group: 64 rows
    const int member = (bx >> 3) & 15;             // j-block within group
    const int b0 = grp * 64;
    const int j0 = member * 32;
    const int tid = threadIdx.x;
    const int lane = tid & 63;
    const int w = tid >> 6;
    const int wm = w & 1, wn = w >> 1;
    const int col = lane & 15, quad = lane >> 4;
    const int jj = j0 + wn * 16 + col;

    // [buf][row][k]; row stride 72 halves: frag b128 reads conflict-free.
    __shared__ _Float16 Abuf[2][64][72];

    // ---- loop-invariant state ----
    float bias[4];
    #pragma unroll
    for (int g = 0; g < 4; ++g) bias[g] = b_ih[g * HH + jj] + b_hh[g * HH + jj];

    const int arow = tid >> 2, aseg = (tid & 3) << 4;
    const size_t aoff = (size_t)(b0 + arow) * HH + aseg;
    const _Float16* a0 = h0g + aoff;    // A staging base per h-plane
    const _Float16* a1 = h1g + aoff;

    const half8* WT8 = (const half8*)WT;
    int bidx[4];
    #pragma unroll
    for (int g = 0; g < 4; ++g) bidx[g] = quad * 2048 + g * HH + jj;

    // h store base: rows b0+wm*32+quad*4 (+ tm*16 + reg)
    const size_t soff = (size_t)(b0 + wm * 32 + quad * 4) * HH + jj;
    _Float16* s0 = h0g + soff;
    _Float16* s1 = h1g + soff;

    // per-member flag words, 64B apart
    unsigned* myflag = ctr + (grp * 16 + member) * 16;
    unsigned* pollflag = ctr + (grp * 16 + (lane & 15)) * 16;

    float cv[2][4] = {{0.f,0.f,0.f,0.f},{0.f,0.f,0.f,0.f}};  // c in registers

    const float* mp[2];
    #pragma unroll
    for (int tm = 0; tm < 2; ++tm)
        mp[tm] = msg + (size_t)(b0 + wm * 32 + tm * 16 + col) * TT * VV;

    // chunk-16 (x-projection) B frags: constant across steps, keep in regs
    half8 Bx[4];
    #pragma unroll
    for (int g = 0; g < 4; ++g) Bx[g] = WT8[16 * 8192 + bidx[g]];

    half8 Bs[2][4];
    f32x4 acc[2][4];   // [tm][gate]; at loop entry for step t: bias + x_t@Wih

    // ---- pre-loop: acc for t=0 ----
    {
        float xv[2][8];
        #pragma unroll
        for (int tm = 0; tm < 2; ++tm)
            #pragma unroll
            for (int j = 0; j < 8; ++j) {
                int k = quad * 8 + j;
                xv[tm][j] = (k < VV) ? mp[tm][k] : 0.0f;
            }
        #pragma unroll
        for (int g = 0; g < 4; ++g) {
            f32x4 bv = {bias[g], bias[g], bias[g], bias[g]};
            acc[0][g] = bv;
            acc[1][g] = bv;
        }
        #pragma unroll
        for (int tm = 0; tm < 2; ++tm) {
            half8 xh;
            #pragma unroll
            for (int j = 0; j < 8; ++j) xh[j] = (_Float16)xv[tm][j];
            #pragma unroll
            for (int g = 0; g < 4; ++g)
                acc[tm][g] = __builtin_amdgcn_mfma_f32_16x16x32_f16(xh, Bx[g], acc[tm][g], 0, 0, 0);
        }
    }

    for (int t = 0; t < TT; ++t) {
        if (t > 0) {   // h-projection: 16 K32 chunks over h_{t-1}
            const _Float16* aph = (t & 1) ? a1 : a0;   // hin plane

            // prologue: A chunk0 -> LDS buf0; chunk1 -> ra. (Bs[0]=c0,
            // Bs[1]=c1 were prefetched in the previous barrier window.)
            half8 ra0 = gload_l2(aph);
            half8 ra1 = gload_l2(aph + 8);
            wait_vm0();
            *(half8*)&Abuf[0][arow][aseg]     = ra0;
            *(half8*)&Abuf[0][arow][aseg + 8] = ra1;
            ra0 = gload_l2(aph + 64);
            ra1 = gload_l2(aph + 72);
            bar_lgkm();

            #pragma unroll
            for (int it = 0; it < 8; ++it) {
                const int buf = it & 1;
                #pragma unroll
                for (int kk = 0; kk < 2; ++kk) {
                    const int cc = it * 2 + kk;   // K32 chunk 0..15
                    const int sl = cc & 1;
                    half8 ahf[2];
                    #pragma unroll
                    for (int tm = 0; tm < 2; ++tm)
                        ahf[tm] = *(const half8*)&Abuf[buf][wm * 32 + tm * 16 + col][kk * 32 + quad * 8];
                    #pragma unroll
                    for (int tm = 0; tm < 2; ++tm)
                        #pragma unroll
                        for (int g = 0; g < 4; ++g)
                            acc[tm][g] = __builtin_amdgcn_mfma_f32_16x16x32_f16(ahf[tm], Bs[sl][g], acc[tm][g], 0, 0, 0);
                    const int pf = cc + 2;        // chunks 2..15 in-loop
                    if (pf <= 15) {
                        #pragma unroll
                        for (int g = 0; g < 4; ++g) Bs[sl][g] = WT8[pf * 8192 + bidx[g]];
                    }
                }
                if (it < 7) {
                    wait_vm8();   // ra retired; 8 B loads stay in flight
                    *(half8*)&Abuf[buf ^ 1][arow][aseg]     = ra0;
                    *(half8*)&Abuf[buf ^ 1][arow][aseg + 8] = ra1;
                    if (it < 6) {
                        ra0 = gload_l2(aph + (it + 2) * 64);
                        ra1 = gload_l2(aph + (it + 2) * 64 + 8);
                    }
                    bar_lgkm();
                }
            }
        }

        // ---- cell update: c in registers; plain h stores -> XCD L2 ----
        // C/D layout: col=lane&15 (=n), row=quad*4+reg  [m89]
        _Float16* hop = (t & 1) ? s0 : s1;      // h_t plane
        #pragma unroll
        for (int tm = 0; tm < 2; ++tm)
            #pragma unroll
            for (int reg = 0; reg < 4; ++reg) {
                float i_ = fsigmoid(acc[tm][0][reg]);
                float f_ = fsigmoid(acc[tm][1][reg]);
                float g_ = ftanh(acc[tm][2][reg]);
                float o_ = fsigmoid(acc[tm][3][reg]);
                float cn = __builtin_fmaf(f_, cv[tm][reg], i_ * g_);
                cv[tm][reg] = cn;
                hop[(size_t)(tm * 16 + reg) * HH] = (_Float16)(o_ * ftanh(cn));
            }

        if (t + 1 < TT) {
            // ---- arrival: drain h stores, then one flag store (no RMW) ----
            __syncthreads();   // vmcnt(0): h_t retired into XCD L2
            if (tid == 0) {
                unsigned v = (unsigned)(t + 1);
                asm volatile("global_store_dword %0, %1, off sc0 sc1"
                             :: "v"(myflag), "v"(v) : "memory");
            }

            // ---- overlap window: all h-independent t+1 work ----
            #pragma unroll
            for (int tm = 0; tm < 2; ++tm) mp[tm] += VV;
            float xv[2][8];
            #pragma unroll
            for (int tm = 0; tm < 2; ++tm)
                #pragma unroll
                for (int j = 0; j < 8; ++j) {
                    int k = quad * 8 + j;
                    xv[tm][j] = (k < VV) ? mp[tm][k] : 0.0f;
                }
            #pragma unroll
            for (int g = 0; g < 4; ++g) {
                f32x4 bv = {bias[g], bias[g], bias[g], bias[g]};
                acc[0][g] = bv;
                acc[1][g] = bv;
            }
            #pragma unroll
            for (int tm = 0; tm < 2; ++tm) {
                half8 xh;
                #pragma unroll
                for (int j = 0; j < 8; ++j) xh[j] = (_Float16)xv[tm][j];
                #pragma unroll
                for (int g = 0; g < 4; ++g)
                    acc[tm][g] = __builtin_amdgcn_mfma_f32_16x16x32_f16(xh, Bx[g], acc[tm][g], 0, 0, 0);
            }
            #pragma unroll
            for (int g = 0; g < 4; ++g) {
                Bs[0][g] = WT8[bidx[g]];
                Bs[1][g] = WT8[8192 + bidx[g]];
            }

            // ---- departure: wave0 polls all 16 flags in one load/iter ----
            if (w == 0) {
                const unsigned tgt = (unsigned)(t + 1);
                for (;;) {
                    unsigned f;
                    asm volatile("global_load_dword %0, %1, off sc0 sc1\n\t"
                                 "s_waitcnt vmcnt(0)"
                                 : "=v"(f) : "v"(pollflag) : "memory");
                    if (__all((int)(f >= tgt))) break;
                    __builtin_amdgcn_s_sleep(1);
                }
                __builtin_amdgcn_sched_barrier(0);
            }
            __syncthreads();
        }
    }
}

// out[b, cls] = dot(h, W_fc[cls]) + b_fc[cls]. 4 rows/block.
__global__ __launch_bounds__(256) void fc_kernel(
    const _Float16* __restrict__ h, const float* __restrict__ W_fc,
    const float* __restrict__ b_fc, float* __restrict__ out)
{
    __shared__ float hs[4][HH];
    const int b0 = blockIdx.x * 4;
    for (int i = threadIdx.x; i < 4 * HH; i += 256) {
        int r = i >> 9, k = i & 511;
        hs[r][k] = (float)h[(size_t)(b0 + r) * HH + k];
    }
    __syncthreads();
    const int tid = threadIdx.x;
    if (tid < 2 * NC) {
        int r = tid / NC, cls = tid % NC;
        const float4* wv = (const float4*)(W_fc + (size_t)cls * HH);
        const float4* h0 = (const float4*)hs[r];
        const float4* h1 = (const float4*)hs[r + 2];
        float s0 = 0.0f, s1 = 0.0f;
        #pragma unroll 4
        for (int k = 0; k < HH / 4; ++k) {
            float4 ww = wv[k];
            float4 a0 = h0[k], a1 = h1[k];
            s0 += a0.x * ww.x + a0.y * ww.y + a0.z * ww.z + a0.w * ww.w;
            s1 += a1.x * ww.x + a1.y * ww.y + a1.z * ww.z + a1.w * ww.w;
        }
        out[(size_t)(b0 + r) * NC + cls] = s0 + b_fc[cls];
        out[(size_t)(b0 + r + 2) * NC + cls] = s1 + b_fc[cls];
    }
}

extern "C" void kernel_launch(void* const* d_in, const int* in_sizes, int n_in,
                              void* d_out, int out_size, void* d_ws, size_t ws_size,
                              hipStream_t stream) {
    const float* msg  = (const float*)d_in[0];
    const float* W_ih = (const float*)d_in[1];
    const float* W_hh = (const float*)d_in[2];
    const float* b_ih = (const float*)d_in[3];
    const float* b_hh = (const float*)d_in[4];
    const float* W_fc = (const float*)d_in[5];
    const float* b_fc = (const float*)d_in[6];
    float* out = (float*)d_out;

    // ws: h0 h1 (fp16, 2MB ea) | WT (fp16, 2.23MB) | flags (32KB)
    _Float16* h0 = (_Float16*)d_ws;
    _Float16* h1 = h0 + (size_t)BB * HH;
    _Float16* WT = h1 + (size_t)BB * HH;
    unsigned* ctr = (unsigned*)(WT + (size_t)68 * 2048 * 8);

    hipMemsetAsync(ctr, 0, 32 * 16 * 16 * sizeof(unsigned), stream);

    prep_whh_t<<<512, 256, 0, stream>>>(W_hh, WT);
    prep_wih_t<<<32, 256, 0, stream>>>(W_ih, WT);

    lstm_persist<<<512, 256, 0, stream>>>(msg, WT, b_ih, b_hh, h0, h1, ctr);

    // t=127 (odd) writes h0
    fc_kernel<<<BB / 4, 256, 0, stream>>>(h0, W_fc, b_fc, out);
}